// Round 6
// baseline (3347.504 us; speedup 1.0000x reference)
//
#include <hip/hip_runtime.h>
#include <stdint.h>

#define DEV static __device__ __forceinline__

typedef __attribute__((ext_vector_type(4))) float f32x4;
typedef __attribute__((ext_vector_type(8))) short bf16x8;
typedef __attribute__((ext_vector_type(4))) short s16x4;

// dims
static constexpr int L_ = 6, T_ = 128, NE = 32, D_ = 1024, H_ = 16, DH_ = 64, M_ = 128, DI_ = 4096;
static constexpr int KLEN = M_ + T_;   // 256
static constexpr int TN = T_ * NE;     // 4096
static constexpr int NB = NE * H_;     // 512 attention batches

DEV unsigned short f2bf(float f) {
  unsigned u = __builtin_bit_cast(unsigned, f);
  u += 0x7FFFu + ((u >> 16) & 1u);
  return (unsigned short)(u >> 16);
}
DEV float bf2f(unsigned short h) {
  unsigned u = ((unsigned)h) << 16;
  return __builtin_bit_cast(float, u);
}

DEV void gload16(const unsigned short* g, unsigned short* lds) {
  __builtin_amdgcn_global_load_lds(
      (const __attribute__((address_space(1))) unsigned int*)g,
      (__attribute__((address_space(3))) unsigned int*)lds, 16, 0, 0);
}

#define WAITV4 asm volatile("s_waitcnt vmcnt(4)" ::: "memory")
#define WAITV0 asm volatile("s_waitcnt vmcnt(0)" ::: "memory")
#define BAR    asm volatile("s_barrier" ::: "memory")

// ===========================================================================
// 256x256 / BK=64 / 8-wave (2Mx4N) pipelined core, 4 phases per K-tile.
// LDS: 2 buf x {Ah0,Ah1,Bh0,Bh1} x 16KB = 128KB. Half-tile = 128 rows x 64
// cols bf16 (128B/row), T2 XOR-swizzled (chunk ^= row&7).
// Phase schedule (per K-tile kt, buffer p=kt&1):
//  ph0: read A-quartet0 + B-lo frags; stage Ah0(kt+1)->buf p^1 | BAR | 16 MFMA | BAR
//  ph1: read B-hi frags;              stage Ah1(kt+1)->buf p^1 | BAR | 16 MFMA | BAR
//  ph2: read A-quartet1;              stage Bh0(kt+2)->buf p   | BAR | 16 MFMA | BAR
//  ph3:                               stage Bh1(kt+2)->buf p; vmcnt(4) | BAR | 16 MFMA | BAR
// Region-recycle safety: B-halves of buf p are last ds_read in ph1, A-halves
// in ph2; overwrites are issued ph2+ (B) and next-tile ph0+ (A), always after
// the end-of-phase barrier that retires those reads. vmcnt(4) at ph3 keeps
// only the 4 newest loads (Bh(kt+2)) outstanding -> tile kt+1 fully landed.
// ===========================================================================
DEV void stage_half(const unsigned short* g, int ld, unsigned short* lbase, int t) {
#pragma unroll
  for (int r = 0; r < 2; ++r) {
    const int obb = r * 8192 + (t >> 6) * 1024;   // wave-uniform byte base
    const int ob  = obb + ((t & 63) << 4);
    const int row = ob >> 7;                      // 128 B per row
    const int col = (((ob >> 4) & 7) ^ (row & 7)) << 3;  // pre-swizzled src
    gload16(g + (size_t)row * ld + col, lbase + (obb >> 1));
  }
}

DEV bf16x8 ldsfrag(const unsigned short* base, int row, int kk, int lgr) {
  const int byte = ((row << 7) + (kk << 6) + (lgr << 4)) ^ ((row & 7) << 4);
  return *(const bf16x8*)((const char*)base + byte);
}

DEV void gemm256_pipe(const unsigned short* __restrict__ Ab, int lda,
                      const unsigned short* __restrict__ Bb, int ldb,
                      unsigned short* lds, int m0, int n0, int NT, int t,
                      f32x4 acc[8][4])
{
  const int w = t >> 6, l = t & 63;
  const int wm = w >> 2, wn = w & 3;
  const int lan = l & 15, lgr = l >> 4;

  unsigned short* A0h[2] = { lds + 0,              lds + 32768 };          // Ah0 per buf
  unsigned short* A1h[2] = { lds + 8192,           lds + 32768 + 8192 };   // Ah1
  unsigned short* B0h[2] = { lds + 16384,          lds + 32768 + 16384 };  // Bh0
  unsigned short* B1h[2] = { lds + 16384 + 8192,   lds + 32768 + 16384 + 8192 };

  // prologue: tile0 (B then A), then B of tile1; wait oldest 8 -> tile0 ready
  stage_half(Bb + (size_t)n0 * ldb,              ldb, B0h[0], t);
  stage_half(Bb + (size_t)(n0 + 128) * ldb,      ldb, B1h[0], t);
  stage_half(Ab + (size_t)m0 * lda,              lda, A0h[0], t);
  stage_half(Ab + (size_t)(m0 + 128) * lda,      lda, A1h[0], t);
  if (NT > 1) {
    stage_half(Bb + (size_t)n0 * ldb + 64,       ldb, B0h[1], t);
    stage_half(Bb + (size_t)(n0 + 128) * ldb + 64, ldb, B1h[1], t);
    WAITV4;
  } else {
    WAITV0;
  }
  BAR;

  for (int kt = 0; kt < NT; ++kt) {
    const int p = kt & 1;
    const unsigned short* A_ = (wm == 0) ? A0h[p] : A1h[p];
    const unsigned short* B_ = ((wn >> 1) == 0) ? B0h[p] : B1h[p];
    const int br0 = (wn & 1) * 64;
    bf16x8 av[8], bv[8];

    // ---------- phase 0 ----------
#pragma unroll
    for (int m = 0; m < 4; ++m)
#pragma unroll
      for (int kk = 0; kk < 2; ++kk)
        av[m * 2 + kk] = ldsfrag(A_, m * 16 + lan, kk, lgr);
#pragma unroll
    for (int n = 0; n < 2; ++n)
#pragma unroll
      for (int kk = 0; kk < 2; ++kk)
        bv[n * 2 + kk] = ldsfrag(B_, br0 + n * 16 + lan, kk, lgr);
    if (kt + 1 < NT)
      stage_half(Ab + (size_t)m0 * lda + (kt + 1) * 64, lda, A0h[p ^ 1], t);
    BAR;
    __builtin_amdgcn_s_setprio(1);
#pragma unroll
    for (int m = 0; m < 4; ++m)
#pragma unroll
      for (int n = 0; n < 2; ++n)
#pragma unroll
        for (int kk = 0; kk < 2; ++kk)
          acc[m][n] = __builtin_amdgcn_mfma_f32_16x16x32_bf16(av[m*2+kk], bv[n*2+kk], acc[m][n], 0, 0, 0);
    __builtin_amdgcn_s_setprio(0);
    BAR;

    // ---------- phase 1 ----------
#pragma unroll
    for (int n = 0; n < 2; ++n)
#pragma unroll
      for (int kk = 0; kk < 2; ++kk)
        bv[4 + n * 2 + kk] = ldsfrag(B_, br0 + 32 + n * 16 + lan, kk, lgr);
    if (kt + 1 < NT)
      stage_half(Ab + (size_t)(m0 + 128) * lda + (kt + 1) * 64, lda, A1h[p ^ 1], t);
    BAR;
    __builtin_amdgcn_s_setprio(1);
#pragma unroll
    for (int m = 0; m < 4; ++m)
#pragma unroll
      for (int n = 0; n < 2; ++n)
#pragma unroll
        for (int kk = 0; kk < 2; ++kk)
          acc[m][2 + n] = __builtin_amdgcn_mfma_f32_16x16x32_bf16(av[m*2+kk], bv[4+n*2+kk], acc[m][2+n], 0, 0, 0);
    __builtin_amdgcn_s_setprio(0);
    BAR;

    // ---------- phase 2 ----------
#pragma unroll
    for (int m = 0; m < 4; ++m)
#pragma unroll
      for (int kk = 0; kk < 2; ++kk)
        av[m * 2 + kk] = ldsfrag(A_, 64 + m * 16 + lan, kk, lgr);
    if (kt + 2 < NT)
      stage_half(Bb + (size_t)n0 * ldb + (kt + 2) * 64, ldb, B0h[p], t);
    BAR;
    __builtin_amdgcn_s_setprio(1);
#pragma unroll
    for (int m = 0; m < 4; ++m)
#pragma unroll
      for (int n = 0; n < 2; ++n)
#pragma unroll
        for (int kk = 0; kk < 2; ++kk)
          acc[4 + m][2 + n] = __builtin_amdgcn_mfma_f32_16x16x32_bf16(av[m*2+kk], bv[4+n*2+kk], acc[4+m][2+n], 0, 0, 0);
    __builtin_amdgcn_s_setprio(0);
    BAR;

    // ---------- phase 3 ----------
    if (kt + 2 < NT)
      stage_half(Bb + (size_t)(n0 + 128) * ldb + (kt + 2) * 64, ldb, B1h[p], t);
    if (kt + 2 < NT) { WAITV4; }
    else if (kt + 1 < NT) { WAITV0; }
    BAR;
    __builtin_amdgcn_s_setprio(1);
#pragma unroll
    for (int m = 0; m < 4; ++m)
#pragma unroll
      for (int n = 0; n < 2; ++n)
#pragma unroll
        for (int kk = 0; kk < 2; ++kk)
          acc[4 + m][n] = __builtin_amdgcn_mfma_f32_16x16x32_bf16(av[m*2+kk], bv[n*2+kk], acc[4+m][n], 0, 0, 0);
    __builtin_amdgcn_s_setprio(0);
    BAR;
  }
}

// Generic 256x256 GEMM, optional split-K via blockIdx.z.
// EPI: 0=f32 out, 2=bf16(bias+relu)
template <int EPI>
__global__ __launch_bounds__(512) void gemm256_bt(
    const unsigned short* __restrict__ A, int lda, int sAh,
    const unsigned short* __restrict__ B, int ldb, int sBh,
    void* __restrict__ Cv, int ldc, int sC,
    const float* __restrict__ bias, int nK)
{
  __shared__ unsigned short lds[65536];
  const int z = blockIdx.z;
  const int m0 = blockIdx.y * 256, n0 = blockIdx.x * 256;
  const int t = threadIdx.x;

  f32x4 acc[8][4];
#pragma unroll
  for (int m = 0; m < 8; ++m)
#pragma unroll
    for (int n = 0; n < 4; ++n) acc[m][n] = (f32x4){0.f, 0.f, 0.f, 0.f};

  gemm256_pipe(A + (size_t)z * sAh, lda, B + (size_t)z * sBh, ldb,
               lds, m0, n0, nK, t, acc);

  const int w = t >> 6, l = t & 63;
  const int wm = w >> 2, wn = w & 3, lan = l & 15, lgr = l >> 4;
  const size_t zc = (size_t)z * sC;
#pragma unroll
  for (int m = 0; m < 8; ++m) {
    const int row = m0 + wm * 128 + m * 16 + lgr * 4;
#pragma unroll
    for (int n = 0; n < 4; ++n) {
      const int col = n0 + wn * 64 + n * 16 + lan;
      const float bcol = (EPI >= 2) ? bias[col] : 0.f;
#pragma unroll
      for (int e = 0; e < 4; ++e) {
        float v = acc[m][n][e];
        const size_t idx = zc + (size_t)(row + e) * ldc + col;
        if (EPI == 0) {
          ((float*)Cv)[idx] = v;
        } else {
          v += bcol; v = v > 0.f ? v : 0.f;
          ((unsigned short*)Cv)[idx] = f2bf(v);
        }
      }
    }
  }
}

// Fused k|v|q|r projection on 256x256 tiles (324 blocks).
__global__ __launch_bounds__(512) void gemm256_proj(
    const unsigned short* __restrict__ catA, const unsigned short* __restrict__ wt,
    unsigned short* __restrict__ kb, unsigned short* __restrict__ vb,
    unsigned short* __restrict__ qw, unsigned short* __restrict__ qr,
    unsigned short* __restrict__ rb,
    const float* __restrict__ rwb, const float* __restrict__ rrb)
{
  __shared__ unsigned short lds[65536];
  const int id = blockIdx.x;
  int by, bx;
  if (id < 256)      { by = id >> 3;                 bx = id & 7; }
  else if (id < 320) { const int u = id - 256; by = 16 + (u >> 2); bx = 8 + (u & 3); }
  else               { const int u = id - 320; by = 32;            bx = 12 + (u & 3); }
  const int m0 = by * 256, n0 = bx * 256;
  const int t = threadIdx.x;

  f32x4 acc[8][4];
#pragma unroll
  for (int m = 0; m < 8; ++m)
#pragma unroll
    for (int n = 0; n < 4; ++n) acc[m][n] = (f32x4){0.f, 0.f, 0.f, 0.f};

  gemm256_pipe(catA, 1024, wt, 1024, lds, m0, n0, 16, t, acc);

  const int w = t >> 6, l = t & 63;
  const int wm = w >> 2, wn = w & 3, lan = l & 15, lgr = l >> 4;
#pragma unroll
  for (int m = 0; m < 8; ++m) {
    const int row = m0 + wm * 128 + m * 16 + lgr * 4;
#pragma unroll
    for (int n = 0; n < 4; ++n) {
      const int col = n0 + wn * 64 + n * 16 + lan;
#pragma unroll
      for (int e = 0; e < 4; ++e) {
        const float v = acc[m][n][e];
        const int r = row + e;
        if (col < 1024) {
          kb[(size_t)r * 1024 + col] = f2bf(v);
        } else if (col < 2048) {
          vb[(size_t)r * 1024 + col - 1024] = f2bf(v);
        } else if (col < 3072) {
          const int c = col - 2048;
          const size_t o = (size_t)(r - 4096) * 1024 + c;
          qw[o] = f2bf(v + rwb[c]);
          qr[o] = f2bf(v + rrb[c]);
        } else {
          const int c = col - 3072;
          rb[(size_t)(r - 8192) * 1024 + c] = f2bf(v);
        }
      }
    }
  }
}

// ===========================================================================
// 128x128 2-phase core (scores K=64, o-proj split-K)
// ===========================================================================
DEV void stage128(const unsigned short* __restrict__ Ab, int lda,
                  const unsigned short* __restrict__ Bb, int ldb,
                  unsigned short* lA, unsigned short* lB,
                  int m0, int n0, int k0, int w, int l)
{
#pragma unroll
  for (int i = 0; i < 4; ++i) {
    const int obb = i * 4096 + w * 1024;
    const int ob  = obb + (l << 4);
    const int row = ob >> 7;
    const int col = (((ob >> 4) & 7) ^ (row & 7)) << 3;
    gload16(Ab + (size_t)(m0 + row) * lda + k0 + col, lA + (obb >> 1));
    gload16(Bb + (size_t)(n0 + row) * ldb + k0 + col, lB + (obb >> 1));
  }
}

DEV void compute128(const unsigned short* lA, const unsigned short* lB,
                    int w, int l, f32x4 acc[4][4])
{
  const int wr = (w >> 1) * 64, wc = (w & 1) * 64;
  const int lan = l & 15, lgr = l >> 4;
#pragma unroll
  for (int ks = 0; ks < 2; ++ks) {
    bf16x8 av[4], bv[4];
#pragma unroll
    for (int m = 0; m < 4; ++m) {
      const int row = wr + m * 16 + lan;
      const int byte = ((row << 7) + (ks << 6) + (lgr << 4)) ^ ((row & 7) << 4);
      av[m] = *(const bf16x8*)((const char*)lA + byte);
    }
#pragma unroll
    for (int n = 0; n < 4; ++n) {
      const int row = wc + n * 16 + lan;
      const int byte = ((row << 7) + (ks << 6) + (lgr << 4)) ^ ((row & 7) << 4);
      bv[n] = *(const bf16x8*)((const char*)lB + byte);
    }
#pragma unroll
    for (int m = 0; m < 4; ++m)
#pragma unroll
      for (int n = 0; n < 4; ++n)
        acc[m][n] = __builtin_amdgcn_mfma_f32_16x16x32_bf16(av[m], bv[n], acc[m][n], 0, 0, 0);
  }
}

DEV void gemm128_2ph(const unsigned short* __restrict__ Ab, int lda,
                     const unsigned short* __restrict__ Bb, int ldb,
                     unsigned short (*shA)[8192], unsigned short (*shB)[8192],
                     int m0, int n0, int nK, int w, int l, f32x4 acc[4][4])
{
  stage128(Ab, lda, Bb, ldb, shA[0], shB[0], m0, n0, 0, w, l);
  WAITV0;
  __syncthreads();
  int cur = 0;
  for (int kt = 0; kt < nK; ++kt) {
    if (kt + 1 < nK)
      stage128(Ab, lda, Bb, ldb, shA[cur ^ 1], shB[cur ^ 1], m0, n0, (kt + 1) * 64, w, l);
    compute128(shA[cur], shB[cur], w, l, acc);
    WAITV0;
    __syncthreads();
    cur ^= 1;
  }
}

// Generic batched GEMM on 128^2 core (used for o-proj split-K).
template <int EPI>
__global__ __launch_bounds__(256) void gemm_bt(
    const unsigned short* __restrict__ A, int lda, int sAn, int sAh,
    const unsigned short* __restrict__ B, int ldb, int sBn, int sBh,
    void* __restrict__ Cv, int ldc, int sC,
    const float* __restrict__ bias, int nK, int Hb)
{
  __shared__ unsigned short shA[2][8192];
  __shared__ unsigned short shB[2][8192];

  const int z = blockIdx.z;
  const int bn = z / Hb, bh = z % Hb;
  const unsigned short* Ab = A + (size_t)bn * sAn + (size_t)bh * sAh;
  const unsigned short* Bb = B + (size_t)bn * sBn + (size_t)bh * sBh;
  const int m0 = blockIdx.y * 128;
  const int n0 = blockIdx.x * 128;

  const int t = threadIdx.x;
  const int w = t >> 6, l = t & 63;
  const int wr = (w >> 1) * 64, wc = (w & 1) * 64;
  const int lan = l & 15, lgr = l >> 4;

  f32x4 acc[4][4];
#pragma unroll
  for (int m = 0; m < 4; ++m)
#pragma unroll
    for (int n = 0; n < 4; ++n) acc[m][n] = (f32x4){0.f, 0.f, 0.f, 0.f};

  gemm128_2ph(Ab, lda, Bb, ldb, shA, shB, m0, n0, nK, w, l, acc);

  const int zc = z * sC;
#pragma unroll
  for (int m = 0; m < 4; ++m) {
    const int row = m0 + wr + m * 16 + lgr * 4;
#pragma unroll
    for (int n = 0; n < 4; ++n) {
      const int col = n0 + wc + n * 16 + lan;
      const float bcol = (EPI >= 2) ? bias[col] : 0.f;
#pragma unroll
      for (int e = 0; e < 4; ++e) {
        float v = acc[m][n][e];
        const size_t idx = (size_t)zc + (size_t)(row + e) * ldc + col;
        if (EPI == 0) {
          ((float*)Cv)[idx] = v;
        } else if (EPI == 1) {
          ((unsigned short*)Cv)[idx] = f2bf(v);
        } else if (EPI == 2) {
          v += bcol; v = v > 0.f ? v : 0.f;
          ((unsigned short*)Cv)[idx] = f2bf(v);
        } else {
          ((float*)Cv)[idx] = v + bcol;
        }
      }
    }
  }
}

// Fused AC+BD score GEMMs: grid (4, 512). bx<2 -> AC, bx>=2 -> BD. K=64.
__global__ __launch_bounds__(256) void gemm_scores(
    const unsigned short* __restrict__ qw, const unsigned short* __restrict__ qr,
    const unsigned short* __restrict__ kbf, const unsigned short* __restrict__ rbf,
    unsigned short* __restrict__ AC, unsigned short* __restrict__ BD)
{
  __shared__ unsigned short shA[8192];
  __shared__ unsigned short shB[8192];

  const int bx = blockIdx.x;
  const int z = blockIdx.y;
  const int nn = z >> 4, hh = z & 15;
  const bool isBD = bx >= 2;
  const int n0 = (bx & 1) * 128;
  const unsigned short* Ab = (isBD ? qr : qw) + (size_t)nn * 1024 + hh * 64;
  const unsigned short* Bb = isBD ? (rbf + hh * 64)
                                  : (kbf + (size_t)nn * 1024 + hh * 64);
  const int ldb = isBD ? 1024 : (NE * 1024);
  unsigned short* C = (isBD ? BD : AC) + (size_t)z * (T_ * KLEN);

  const int t = threadIdx.x;
  const int w = t >> 6, l = t & 63;
  const int wr = (w >> 1) * 64, wc = (w & 1) * 64;
  const int lan = l & 15, lgr = l >> 4;

  f32x4 acc[4][4];
#pragma unroll
  for (int m = 0; m < 4; ++m)
#pragma unroll
    for (int n = 0; n < 4; ++n) acc[m][n] = (f32x4){0.f, 0.f, 0.f, 0.f};

  stage128(Ab, NE * 1024, Bb, ldb, shA, shB, 0, n0, 0, w, l);
  WAITV0;
  __syncthreads();
  compute128(shA, shB, w, l, acc);

#pragma unroll
  for (int m = 0; m < 4; ++m) {
    const int row = wr + m * 16 + lgr * 4;
#pragma unroll
    for (int n = 0; n < 4; ++n) {
      const int col = n0 + wc + n * 16 + lan;
#pragma unroll
      for (int e = 0; e < 4; ++e)
        C[(size_t)(row + e) * KLEN + col] = f2bf(acc[m][n][e]);
    }
  }
}

// ---------------------------------------------------------------------------
// Fused masked-softmax + PV (P in LDS, XOR-swizzled). One block per z.
// ---------------------------------------------------------------------------
__global__ __launch_bounds__(256) void smpv_kernel(
    const unsigned short* __restrict__ AC, const unsigned short* __restrict__ BD,
    const int* __restrict__ ep, const unsigned short* __restrict__ V,
    unsigned short* __restrict__ O)
{
  __shared__ unsigned short sP[128 * 256];   // 64 KB

  const int z = blockIdx.x;
  const int nn = z >> 4, hh = z & 15;
  const int t = threadIdx.x, w = t >> 6, l = t & 63;
  const int lan = l & 15, lgr = l >> 4;
  const size_t zbase = (size_t)z * (T_ * KLEN);

  const int j0 = l * 4;
  for (int rr = 0; rr < 32; ++rr) {
    const int i = w * 32 + rr;
    const int epi = ep[i * NE + nn];
    const size_t base = zbase + (size_t)i * KLEN;
    s16x4 ac4 = *(const s16x4*)&AC[base + j0];
    float sc[4];
#pragma unroll
    for (int q = 0; q < 4; ++q) {
      const int j = j0 + q;
      int jx = j + (T_ - 1) - i; if (jx > KLEN - 1) jx = KLEN - 1;
      const float bd = bf2f((unsigned short)BD[base + jx]);
      bool allow;
      if (j < M_) {
        allow = (epi == 0);
      } else {
        const int jp = j - M_;
        allow = (jp <= i) && (ep[jp * NE + nn] == epi);
      }
      const float v = (bf2f((unsigned short)ac4[q]) + bd) * 0.125f;
      sc[q] = allow ? v : -1e9f;
    }
    float mx = fmaxf(fmaxf(sc[0], sc[1]), fmaxf(sc[2], sc[3]));
#pragma unroll
    for (int o = 32; o; o >>= 1) mx = fmaxf(mx, __shfl_xor(mx, o));
    float p[4], sum = 0.f;
#pragma unroll
    for (int q = 0; q < 4; ++q) { p[q] = __expf(sc[q] - mx); sum += p[q]; }
#pragma unroll
    for (int o = 32; o; o >>= 1) sum += __shfl_xor(sum, o);
    const float inv = 1.f / sum;
    s16x4 o4;
#pragma unroll
    for (int q = 0; q < 4; ++q) o4[q] = (short)f2bf(p[q] * inv);
    const int swz = ((i >> 2) & 3) * 16;
    *(s16x4*)&sP[i * 256 + (j0 ^ swz)] = o4;
  }
  __syncthreads();

  const int i0 = w * 32;
  const unsigned short* Vz = V + hh * DH_;

  f32x4 acc[2][4];
#pragma unroll
  for (int m = 0; m < 2; ++m)
#pragma unroll
    for (int n = 0; n < 4; ++n) acc[m][n] = (f32x4){0.f, 0.f, 0.f, 0.f};

  for (int ks = 0; ks < 8; ++ks) {
    const int kb = ks * 32 + lgr * 8;
    bf16x8 bv[4];
#pragma unroll
    for (int n = 0; n < 4; ++n) {
      const int d = n * 16 + lan;
      bf16x8 tmp;
#pragma unroll
      for (int jj = 0; jj < 8; ++jj)
        tmp[jj] = (short)Vz[(size_t)((kb + jj) * NE + nn) * 1024 + d];
      bv[n] = tmp;
    }
    bf16x8 av[2];
#pragma unroll
    for (int m = 0; m < 2; ++m) {
      const int row = i0 + m * 16 + lan;
      const int swz = ((row >> 2) & 3) * 16;
      av[m] = *(const bf16x8*)&sP[row * 256 + (kb ^ swz)];
    }
#pragma unroll
    for (int m = 0; m < 2; ++m)
#pragma unroll
      for (int n = 0; n < 4; ++n)
        acc[m][n] = __builtin_amdgcn_mfma_f32_16x16x32_bf16(av[m], bv[n], acc[m][n], 0, 0, 0);
  }
#pragma unroll
  for (int m = 0; m < 2; ++m)
#pragma unroll
    for (int n = 0; n < 4; ++n)
#pragma unroll
      for (int e = 0; e < 4; ++e) {
        const int i = i0 + m * 16 + lgr * 4 + e;
        const int d = n * 16 + lan;
        O[(size_t)(i * NE + nn) * 1024 + hh * DH_ + d] = f2bf(acc[m][n][e]);
      }
}

// ---------------------------------------------------------------------------
__global__ __launch_bounds__(256) void transpose_kernel(
    const float* __restrict__ W, unsigned short* __restrict__ WT, int Kd, int Nd)
{
  __shared__ float tile[32][33];
  const int tx = threadIdx.x & 31, ty = threadIdx.x >> 5;
  const int nIn = blockIdx.x * 32 + tx;
  const int kBase = blockIdx.y * 32;
#pragma unroll
  for (int r = 0; r < 32; r += 8)
    tile[ty + r][tx] = W[(size_t)(kBase + ty + r) * Nd + nIn];
  __syncthreads();
#pragma unroll
  for (int r = 0; r < 32; r += 8)
    WT[(size_t)(blockIdx.x * 32 + ty + r) * Kd + kBase + tx] = f2bf(tile[tx][ty + r]);
}

__global__ __launch_bounds__(256) void transpose5_kernel(
    const float* __restrict__ Wk, const float* __restrict__ Wv,
    const float* __restrict__ Wq, const float* __restrict__ Wr,
    const float* __restrict__ Wo,
    unsigned short* __restrict__ wtAll, unsigned short* __restrict__ wto)
{
  __shared__ float tile[32][33];
  const int zz = blockIdx.z;
  const float* W = (zz == 0) ? Wk : (zz == 1) ? Wv : (zz == 2) ? Wq : (zz == 3) ? Wr : Wo;
  unsigned short* WT = (zz == 4) ? wto : (wtAll + (size_t)zz * 1024 * 1024);
  const int tx = threadIdx.x & 31, ty = threadIdx.x >> 5;
  const int nIn = blockIdx.x * 32 + tx;
  const int kBase = blockIdx.y * 32;
#pragma unroll
  for (int r = 0; r < 32; r += 8)
    tile[ty + r][tx] = W[(size_t)(kBase + ty + r) * 1024 + nIn];
  __syncthreads();
#pragma unroll
  for (int r = 0; r < 32; r += 8)
    WT[(size_t)(blockIdx.x * 32 + ty + r) * 1024 + kBase + tx] = f2bf(tile[tx][ty + r]);
}

__global__ __launch_bounds__(256) void catmem_kernel(
    const float* __restrict__ mems_l, const float* __restrict__ masks,
    unsigned short* __restrict__ cat)
{
  const int idx = blockIdx.x * 256 + threadIdx.x;
  const int d = idx & 1023;
  const int r = idx >> 10;
  const int nn = r & 31, j = r >> 5;
  const float mk0 = masks[nn];
  cat[idx] = f2bf(mems_l[(size_t)(nn * M_ + j) * 1024 + d] * mk0);
}

__global__ __launch_bounds__(256) void hprep_kernel(
    const float* __restrict__ x, const float* __restrict__ ctx,
    float* __restrict__ h, unsigned short* __restrict__ catUp)
{
  const int idx = blockIdx.x * 256 + threadIdx.x;
  const float v = x[idx] + ctx[idx];
  h[idx] = v;
  catUp[idx] = f2bf(v);
}

__global__ __launch_bounds__(256) void rpos_kernel(unsigned short* __restrict__ R)
{
  const int idx = blockIdx.x * 256 + threadIdx.x;
  const int d = idx & 1023, j = idx >> 10;
  const float pos = (float)(KLEN - 1 - j);
  const int f = d & 511;
  const float inv_freq = __expf(-((float)(2 * f) * (1.f / 1024.f)) * 9.210340371976184f);
  const float ang = pos * inv_freq;
  const float v = (d < 512) ? sinf(ang) : cosf(ang);
  R[idx] = f2bf(v);
}

__global__ void ep_kernel(const float* __restrict__ masks, int* __restrict__ ep)
{
  const int nn = threadIdx.x;
  if (nn < NE) {
    int c = 0;
    for (int i = 0; i < T_; ++i) {
      c += (masks[i * NE + nn] == 0.f) ? 1 : 0;
      ep[i * NE + nn] = c;
    }
  }
}

// y = LN(a + sum_{i<NP} parts[i] + bias) * g + b
template <int NP>
__global__ __launch_bounds__(256) void ln_kernel(
    const float* __restrict__ a, const float* __restrict__ parts, size_t pstride,
    const float* __restrict__ bias,
    const float* __restrict__ g, const float* __restrict__ bb,
    float* __restrict__ outf, unsigned short* __restrict__ outbf)
{
  const int row = blockIdx.x;
  const int t = threadIdx.x, w = t >> 6, l = t & 63;
  const int c = t * 4;
  const size_t base = (size_t)row * 1024;
  f32x4 v = *(const f32x4*)&a[base + c];
#pragma unroll
  for (int i = 0; i < NP; ++i)
    v = v + *(const f32x4*)&parts[i * pstride + base + c];
  if (bias) v = v + *(const f32x4*)&bias[c];
  float s = v[0] + v[1] + v[2] + v[3];
#pragma unroll
  for (int o = 32; o; o >>= 1) s += __shfl_xor(s, o);
  __shared__ float red[8];
  if (l == 0) red[w] = s;
  __syncthreads();
  s = red[0] + red[1] + red[2] + red[3];
  const float mu = s * (1.f / 1024.f);
  f32x4 dv = v - mu;
  float s2 = dv[0]*dv[0] + dv[1]*dv[1] + dv[2]*dv[2] + dv[3]*dv[3];
#pragma unroll
  for (int o = 32; o; o >>= 1) s2 += __shfl_xor(s2, o);
  if (l == 0) red[4 + w] = s2;
  __syncthreads();
  s2 = red[4] + red[5] + red[6] + red[7];
  const float inv = rsqrtf(s2 * (1.f / 1024.f) + 1e-5f);
  f32x4 y;
#pragma unroll
  for (int q = 0; q < 4; ++q) y[q] = dv[q] * inv * g[c + q] + bb[c + q];
  *(f32x4*)&outf[base + c] = y;
  if (outbf) {
    s16x4 o4;
#pragma unroll
    for (int q = 0; q < 4; ++q) o4[q] = (short)f2bf(y[q]);
    *(s16x4*)&outbf[base + c] = o4;
  }
}

// ---------------------------------------------------------------------------
extern "C" void kernel_launch(void* const* d_in, const int* in_sizes, int n_in,
                              void* d_out, int out_size, void* d_ws, size_t ws_size,
                              hipStream_t stream)
{
  (void)in_sizes; (void)n_in; (void)out_size; (void)ws_size;
  const float* x    = (const float*)d_in[0];
  const float* ctx  = (const float*)d_in[1];
  const float* mems = (const float*)d_in[2];
  const float* masks= (const float*)d_in[3];
  const float* Wq   = (const float*)d_in[4];
  const float* Wk   = (const float*)d_in[5];
  const float* Wv   = (const float*)d_in[6];
  const float* Wr   = (const float*)d_in[7];
  const float* Wo   = (const float*)d_in[8];
  const float* W1   = (const float*)d_in[9];
  const float* b1   = (const float*)d_in[10];
  const float* W2   = (const float*)d_in[11];
  const float* b2   = (const float*)d_in[12];
  const float* ln1g = (const float*)d_in[13];
  const float* ln1b = (const float*)d_in[14];
  const float* ln2g = (const float*)d_in[15];
  const float* ln2b = (const float*)d_in[16];
  const float* rwb  = (const float*)d_in[17];
  const float* rrb  = (const float*)d_in[18];

  char* ws = (char*)d_ws;
  size_t off = 0;
  auto alloc = [&](size_t bytes) {
    char* p = ws + off;
    off += (bytes + 255) & ~(size_t)255;
    return p;
  };
  unsigned short* wtAll = (unsigned short*)alloc(4096u * 1024 * 2);  // [Wk|Wv|Wq|Wr]^T
  unsigned short* wto = (unsigned short*)alloc(1024u * 1024 * 2);
  unsigned short* wt1 = (unsigned short*)alloc(4096u * 1024 * 2);
  unsigned short* wt2 = (unsigned short*)alloc(4096u * 1024 * 2);
  unsigned short* cat = (unsigned short*)alloc((size_t)(KLEN * NE + 256) * 1024 * 2);
  unsigned short* rbf = (unsigned short*)alloc((size_t)KLEN * 1024 * 2);
  int*            epb = (int*)alloc((size_t)T_ * NE * 4);
  float*          h   = (float*)alloc((size_t)TN * 1024 * 4);
  float*          h1  = (float*)alloc((size_t)TN * 1024 * 4);
  unsigned short* qw  = (unsigned short*)alloc((size_t)TN * 1024 * 2);   // alias: h1_bf
  unsigned short* qr  = (unsigned short*)alloc((size_t)TN * 1024 * 2);
  unsigned short* kbf = (unsigned short*)alloc((size_t)KLEN * NE * 1024 * 2);
  unsigned short* vbf = (unsigned short*)alloc((size_t)KLEN * NE * 1024 * 2);
  unsigned short* ACb = (unsigned short*)alloc((size_t)NB * T_ * KLEN * 2); // alias: f1
  unsigned short* obf = (unsigned short*)alloc((size_t)TN * 1024 * 2);
  unsigned short* BDb = (unsigned short*)alloc((size_t)NB * T_ * KLEN * 2); // alias: part 0,1
  float*          pex = (float*)alloc((size_t)2 * TN * 1024 * 4);          // part 2,3

  (void)pex;
  unsigned short* catUp = cat + (size_t)M_ * NE * 1024;     // h rows (4096..8191)
  unsigned short* catR  = cat + (size_t)KLEN * NE * 1024;   // R rows (8192..8447)
  unsigned short* f1 = ACb;                 // W1 out (AC dead after smpv)
  float* part = (float*)BDb;                // partials: BDb (2x) + pex (2x), contiguous
  unsigned short* h1bf = qw;                // qw dead after scores gemm

  rpos_kernel<<<KLEN * 1024 / 256, 256, 0, stream>>>(catR);
  ep_kernel<<<1, 64, 0, stream>>>(masks, epb);
  hprep_kernel<<<TN * 1024 / 256, 256, 0, stream>>>(x, ctx, h, catUp);

  for (int l = 0; l < L_; ++l) {
    const size_t wOff = (size_t)l * 1024 * 1024;
    const size_t wOffBig = (size_t)l * 1024 * 4096;
    transpose5_kernel<<<dim3(32, 32, 5), 256, 0, stream>>>(
        Wk + wOff, Wv + wOff, Wq + wOff, Wr + wOff, Wo + wOff, wtAll, wto);
    transpose_kernel<<<dim3(128, 32), 256, 0, stream>>>(W1 + wOffBig, wt1, 1024, 4096);
    transpose_kernel<<<dim3(32, 128), 256, 0, stream>>>(W2 + wOffBig, wt2, 4096, 1024);
    catmem_kernel<<<M_ * NE * 1024 / 256, 256, 0, stream>>>(
        mems + (size_t)l * NE * M_ * 1024, masks, cat);

    // fused k|v|q|r projection: 324 blocks of 256^2, pipelined core
    gemm256_proj<<<324, 512, 0, stream>>>(cat, wtAll, kbf, vbf, qw, qr, rbf, rwb, rrb);

    // fused AC+BD score GEMMs
    gemm_scores<<<dim3(4, 512), 256, 0, stream>>>(qw, qr, kbf, rbf, ACb, BDb);

    // fused masked-softmax + PV
    smpv_kernel<<<NB, 256, 0, stream>>>(ACb, BDb, epb, vbf, obf);

    // output projection, split-K=2 (128^2 core) -> f32 partials; reduce in LN1
    gemm_bt<0><<<dim3(8, 32, 2), 256, 0, stream>>>(obf, 1024, 0, 512,
                                                   wto, 1024, 0, 512,
                                                   part, 1024, TN * 1024, nullptr, 8, 2);
    ln_kernel<2><<<TN, 256, 0, stream>>>(h, part, (size_t)TN * 1024, nullptr,
                                         ln1g + l * 1024, ln1b + l * 1024, h1, h1bf);

    // FFN: W1 on 256^2 pipelined core (bias+relu fused)
    gemm256_bt<2><<<dim3(16, 16, 1), 512, 0, stream>>>(
        h1bf, 1024, 0, wt1, 1024, 0,
        f1, 4096, 0, b1 + l * 4096, 16);
    // W2 split-K=4 on 256^2 core -> 4 f32 partials; reduce in LN2
    gemm256_bt<0><<<dim3(4, 16, 4), 512, 0, stream>>>(
        f1, 4096, 1024, wt2, 4096, 1024,
        part, 1024, TN * 1024, nullptr, 16);
    ln_kernel<4><<<TN, 256, 0, stream>>>(h1, part, (size_t)TN * 1024, b2 + l * 1024,
                                         ln2g + l * 1024, ln2b + l * 1024,
                                         (l == L_ - 1) ? (float*)d_out : h, catUp);
  }
}

// Round 7
// 1911.737 us; speedup vs baseline: 1.7510x; 1.7510x over previous
//
#include <hip/hip_runtime.h>
#include <stdint.h>

#define DEV static __device__ __forceinline__

typedef __attribute__((ext_vector_type(4))) float f32x4;
typedef __attribute__((ext_vector_type(8))) short bf16x8;
typedef __attribute__((ext_vector_type(4))) short s16x4;

// dims
static constexpr int L_ = 6, T_ = 128, NE = 32, D_ = 1024, H_ = 16, DH_ = 64, M_ = 128, DI_ = 4096;
static constexpr int KLEN = M_ + T_;   // 256
static constexpr int TN = T_ * NE;     // 4096
static constexpr int NB = NE * H_;     // 512 attention batches

DEV unsigned short f2bf(float f) {
  unsigned u = __builtin_bit_cast(unsigned, f);
  u += 0x7FFFu + ((u >> 16) & 1u);
  return (unsigned short)(u >> 16);
}
DEV float bf2f(unsigned short h) {
  unsigned u = ((unsigned)h) << 16;
  return __builtin_bit_cast(float, u);
}

DEV void gload16(const unsigned short* g, unsigned short* lds) {
  __builtin_amdgcn_global_load_lds(
      (const __attribute__((address_space(1))) unsigned int*)g,
      (__attribute__((address_space(3))) unsigned int*)lds, 16, 0, 0);
}

#define WAITV0 asm volatile("s_waitcnt vmcnt(0)" ::: "memory")

// ---------------------------------------------------------------------------
// 128x128 tile core, BK=64, 4 waves (2x2), mfma_f32_16x16x32_bf16.
// T2 XOR-swizzle (both-sides). 2-phase: STAGE(t+1) before compute(t).
// ---------------------------------------------------------------------------
DEV void stage128(const unsigned short* __restrict__ Ab, int lda,
                  const unsigned short* __restrict__ Bb, int ldb,
                  unsigned short* lA, unsigned short* lB,
                  int m0, int n0, int k0, int w, int l)
{
#pragma unroll
  for (int i = 0; i < 4; ++i) {
    const int obb = i * 4096 + w * 1024;
    const int ob  = obb + (l << 4);
    const int row = ob >> 7;
    const int col = (((ob >> 4) & 7) ^ (row & 7)) << 3;
    gload16(Ab + (size_t)(m0 + row) * lda + k0 + col, lA + (obb >> 1));
    gload16(Bb + (size_t)(n0 + row) * ldb + k0 + col, lB + (obb >> 1));
  }
}

DEV void compute128(const unsigned short* lA, const unsigned short* lB,
                    int w, int l, f32x4 acc[4][4])
{
  const int wr = (w >> 1) * 64, wc = (w & 1) * 64;
  const int lan = l & 15, lgr = l >> 4;
#pragma unroll
  for (int ks = 0; ks < 2; ++ks) {
    bf16x8 av[4], bv[4];
#pragma unroll
    for (int m = 0; m < 4; ++m) {
      const int row = wr + m * 16 + lan;
      const int byte = ((row << 7) + (ks << 6) + (lgr << 4)) ^ ((row & 7) << 4);
      av[m] = *(const bf16x8*)((const char*)lA + byte);
    }
#pragma unroll
    for (int n = 0; n < 4; ++n) {
      const int row = wc + n * 16 + lan;
      const int byte = ((row << 7) + (ks << 6) + (lgr << 4)) ^ ((row & 7) << 4);
      bv[n] = *(const bf16x8*)((const char*)lB + byte);
    }
#pragma unroll
    for (int m = 0; m < 4; ++m)
#pragma unroll
      for (int n = 0; n < 4; ++n)
        acc[m][n] = __builtin_amdgcn_mfma_f32_16x16x32_bf16(av[m], bv[n], acc[m][n], 0, 0, 0);
  }
}

DEV void gemm128_2ph(const unsigned short* __restrict__ Ab, int lda,
                     const unsigned short* __restrict__ Bb, int ldb,
                     unsigned short (*shA)[8192], unsigned short (*shB)[8192],
                     int m0, int n0, int nK, int w, int l, f32x4 acc[4][4])
{
  stage128(Ab, lda, Bb, ldb, shA[0], shB[0], m0, n0, 0, w, l);
  WAITV0;
  __syncthreads();
  int cur = 0;
  for (int kt = 0; kt < nK; ++kt) {
    if (kt + 1 < nK)
      stage128(Ab, lda, Bb, ldb, shA[cur ^ 1], shB[cur ^ 1], m0, n0, (kt + 1) * 64, w, l);
    compute128(shA[cur], shB[cur], w, l, acc);
    WAITV0;
    __syncthreads();
    cur ^= 1;
  }
}

// ---------------------------------------------------------------------------
// Generic batched GEMM: C[M,N] = A[M,K] @ Bt[N,K].
// EPI: 0=f32 out, 1=bf16 out, 2=bf16(bias+relu), 3=f32(bias)
// split-K: Hb=nsplit, sAn=sBn=0, sAh=sBh=K_per_split, sC=M*N.
// ---------------------------------------------------------------------------
template <int EPI>
__global__ __launch_bounds__(256) void gemm_bt(
    const unsigned short* __restrict__ A, int lda, int sAn, int sAh,
    const unsigned short* __restrict__ B, int ldb, int sBn, int sBh,
    void* __restrict__ Cv, int ldc, int sC,
    const float* __restrict__ bias, int nK, int Hb)
{
  __shared__ unsigned short shA[2][8192];
  __shared__ unsigned short shB[2][8192];

  const int z = blockIdx.z;
  const int bn = z / Hb, bh = z % Hb;
  const unsigned short* Ab = A + (size_t)bn * sAn + (size_t)bh * sAh;
  const unsigned short* Bb = B + (size_t)bn * sBn + (size_t)bh * sBh;
  const int m0 = blockIdx.y * 128;
  const int n0 = blockIdx.x * 128;

  const int t = threadIdx.x;
  const int w = t >> 6, l = t & 63;
  const int wr = (w >> 1) * 64, wc = (w & 1) * 64;
  const int lan = l & 15, lgr = l >> 4;

  f32x4 acc[4][4];
#pragma unroll
  for (int m = 0; m < 4; ++m)
#pragma unroll
    for (int n = 0; n < 4; ++n) acc[m][n] = (f32x4){0.f, 0.f, 0.f, 0.f};

  gemm128_2ph(Ab, lda, Bb, ldb, shA, shB, m0, n0, nK, w, l, acc);

  const int zc = z * sC;
#pragma unroll
  for (int m = 0; m < 4; ++m) {
    const int row = m0 + wr + m * 16 + lgr * 4;
#pragma unroll
    for (int n = 0; n < 4; ++n) {
      const int col = n0 + wc + n * 16 + lan;
      const float bcol = (EPI >= 2) ? bias[col] : 0.f;
#pragma unroll
      for (int e = 0; e < 4; ++e) {
        float v = acc[m][n][e];
        const size_t idx = (size_t)zc + (size_t)(row + e) * ldc + col;
        if (EPI == 0) {
          ((float*)Cv)[idx] = v;
        } else if (EPI == 1) {
          ((unsigned short*)Cv)[idx] = f2bf(v);
        } else if (EPI == 2) {
          v += bcol; v = v > 0.f ? v : 0.f;
          ((unsigned short*)Cv)[idx] = f2bf(v);
        } else {
          ((float*)Cv)[idx] = v + bcol;
        }
      }
    }
  }
}

// ---------------------------------------------------------------------------
// Fused projection GEMM: [cat(8192 rows) ; R(256 rows)] @ [Wk|Wv|Wq|Wr]^T
// ---------------------------------------------------------------------------
__global__ __launch_bounds__(256) void gemm_proj(
    const unsigned short* __restrict__ catA, const unsigned short* __restrict__ wt,
    unsigned short* __restrict__ kb, unsigned short* __restrict__ vb,
    unsigned short* __restrict__ qw, unsigned short* __restrict__ qr,
    unsigned short* __restrict__ rb,
    const float* __restrict__ rwb, const float* __restrict__ rrb)
{
  __shared__ unsigned short shA[2][8192];
  __shared__ unsigned short shB[2][8192];

  const int id = blockIdx.x;
  int by, bx;
  if (id < 1024)      { by = id >> 4;               bx = id & 15; }
  else if (id < 1280) { const int u = id - 1024; by = 32 + (u >> 3); bx = 16 + (u & 7); }
  else                { const int u = id - 1280; by = 64 + (u >> 3); bx = 24 + (u & 7); }
  const int m0 = by * 128, n0 = bx * 128;

  const int t = threadIdx.x;
  const int w = t >> 6, l = t & 63;
  const int wr = (w >> 1) * 64, wc = (w & 1) * 64;
  const int lan = l & 15, lgr = l >> 4;

  f32x4 acc[4][4];
#pragma unroll
  for (int m = 0; m < 4; ++m)
#pragma unroll
    for (int n = 0; n < 4; ++n) acc[m][n] = (f32x4){0.f, 0.f, 0.f, 0.f};

  gemm128_2ph(catA, 1024, wt, 1024, shA, shB, m0, n0, 16, w, l, acc);

#pragma unroll
  for (int m = 0; m < 4; ++m) {
    const int row = m0 + wr + m * 16 + lgr * 4;
#pragma unroll
    for (int n = 0; n < 4; ++n) {
      const int col = n0 + wc + n * 16 + lan;
#pragma unroll
      for (int e = 0; e < 4; ++e) {
        const float v = acc[m][n][e];
        const int r = row + e;
        if (col < 1024) {
          kb[(size_t)r * 1024 + col] = f2bf(v);
        } else if (col < 2048) {
          vb[(size_t)r * 1024 + col - 1024] = f2bf(v);
        } else if (col < 3072) {
          const int c = col - 2048;
          const size_t o = (size_t)(r - 4096) * 1024 + c;
          qw[o] = f2bf(v + rwb[c]);
          qr[o] = f2bf(v + rrb[c]);
        } else {
          const int c = col - 3072;
          rb[(size_t)(r - 8192) * 1024 + c] = f2bf(v);
        }
      }
    }
  }
}

// ---------------------------------------------------------------------------
// Fully fused attention: AC + shifted-BD + masked softmax + PV.
// One block per z=(nn,hh), 4 waves; each wave owns 32 q-rows; ZERO barriers
// (all LDS traffic is wave-local). Operand fragments are loaded directly
// from global (L2-resident): contiguous 16B per lane. rel_shift is applied
// at BD-write time: S[i][j'+i-127] += BD[i][j'] (injective per row — the
// exact inverse of the softmax-side gather).
// LDS: 4 waves x 32x256 bf16 = 64 KB (swizzled: elem j ^ ((r>>2)&3)*16).
// ---------------------------------------------------------------------------
__global__ __launch_bounds__(256) void attn_kernel(
    const unsigned short* __restrict__ qw, const unsigned short* __restrict__ qr,
    const unsigned short* __restrict__ kbf, const unsigned short* __restrict__ rbf,
    const int* __restrict__ ep, const unsigned short* __restrict__ V,
    unsigned short* __restrict__ O)
{
  __shared__ unsigned short sS[4][32 * 256];   // 64 KB

  const int z = blockIdx.x;
  const int nn = z >> 4, hh = z & 15;
  const int t = threadIdx.x, w = t >> 6, l = t & 63;
  const int lan = l & 15, lgr = l >> 4;
  const int i0 = w * 32;
  unsigned short* S = sS[w];

  // ---- AC = (q + r_w_bias) . K^T  -> S ----
  bf16x8 av[2][2];
#pragma unroll
  for (int m = 0; m < 2; ++m)
#pragma unroll
    for (int kk = 0; kk < 2; ++kk) {
      const int i = i0 + m * 16 + lan;
      av[m][kk] = *(const bf16x8*)&qw[(size_t)(i * NE + nn) * 1024 + hh * 64 + kk * 32 + lgr * 8];
    }
#pragma unroll
  for (int n = 0; n < 16; ++n) {
    bf16x8 bv[2];
#pragma unroll
    for (int kk = 0; kk < 2; ++kk) {
      const int j = n * 16 + lan;
      bv[kk] = *(const bf16x8*)&kbf[(size_t)(j * NE + nn) * 1024 + hh * 64 + kk * 32 + lgr * 8];
    }
#pragma unroll
    for (int m = 0; m < 2; ++m) {
      f32x4 a4 = (f32x4){0.f, 0.f, 0.f, 0.f};
#pragma unroll
      for (int kk = 0; kk < 2; ++kk)
        a4 = __builtin_amdgcn_mfma_f32_16x16x32_bf16(av[m][kk], bv[kk], a4, 0, 0, 0);
#pragma unroll
      for (int e = 0; e < 4; ++e) {
        const int r = m * 16 + lgr * 4 + e;
        const int j = n * 16 + lan;
        const int swz = ((r >> 2) & 3) * 16;
        S[r * 256 + (j ^ swz)] = f2bf(a4[e]);
      }
    }
  }

  // ---- BD = (q + r_r_bias) . R^T, scatter-add with shift j = j' + i - 127 ----
  bf16x8 bq[2][2];
#pragma unroll
  for (int m = 0; m < 2; ++m)
#pragma unroll
    for (int kk = 0; kk < 2; ++kk) {
      const int i = i0 + m * 16 + lan;
      bq[m][kk] = *(const bf16x8*)&qr[(size_t)(i * NE + nn) * 1024 + hh * 64 + kk * 32 + lgr * 8];
    }
#pragma unroll
  for (int n = 0; n < 16; ++n) {
    bf16x8 bv[2];
#pragma unroll
    for (int kk = 0; kk < 2; ++kk) {
      const int jp = n * 16 + lan;
      bv[kk] = *(const bf16x8*)&rbf[(size_t)jp * 1024 + hh * 64 + kk * 32 + lgr * 8];
    }
#pragma unroll
    for (int m = 0; m < 2; ++m) {
      f32x4 a4 = (f32x4){0.f, 0.f, 0.f, 0.f};
#pragma unroll
      for (int kk = 0; kk < 2; ++kk)
        a4 = __builtin_amdgcn_mfma_f32_16x16x32_bf16(bq[m][kk], bv[kk], a4, 0, 0, 0);
#pragma unroll
      for (int e = 0; e < 4; ++e) {
        const int r = m * 16 + lgr * 4 + e;
        const int i = i0 + r;
        const int jp = n * 16 + lan;
        const int j = jp + i - 127;
        if (j >= 0 && j < 256) {
          const int swz = ((r >> 2) & 3) * 16;
          const int idx = r * 256 + (j ^ swz);
          S[idx] = f2bf(bf2f(S[idx]) + a4[e]);
        }
      }
    }
  }

  // ---- masked softmax, in place (wave-parallel over j, own rows) ----
  const int j0 = l * 4;
  for (int rr = 0; rr < 32; ++rr) {
    const int i = i0 + rr;
    const int epi = ep[i * NE + nn];
    const int swz = ((rr >> 2) & 3) * 16;
    s16x4 s4 = *(const s16x4*)&S[rr * 256 + (j0 ^ swz)];
    float sc[4];
#pragma unroll
    for (int q = 0; q < 4; ++q) {
      const int j = j0 + q;
      bool allow;
      if (j < M_) {
        allow = (epi == 0);
      } else {
        const int jp = j - M_;
        allow = (jp <= i) && (ep[jp * NE + nn] == epi);
      }
      sc[q] = allow ? bf2f((unsigned short)s4[q]) * 0.125f : -1e9f;
    }
    float mx = fmaxf(fmaxf(sc[0], sc[1]), fmaxf(sc[2], sc[3]));
#pragma unroll
    for (int o = 32; o; o >>= 1) mx = fmaxf(mx, __shfl_xor(mx, o));
    float p[4], sum = 0.f;
#pragma unroll
    for (int q = 0; q < 4; ++q) { p[q] = __expf(sc[q] - mx); sum += p[q]; }
#pragma unroll
    for (int o = 32; o; o >>= 1) sum += __shfl_xor(sum, o);
    const float inv = 1.f / sum;
    s16x4 o4;
#pragma unroll
    for (int q = 0; q < 4; ++q) o4[q] = (short)f2bf(p[q] * inv);
    *(s16x4*)&S[rr * 256 + (j0 ^ swz)] = o4;
  }

  // ---- PV: O[i,d] = sum_j P[i,j] * V[j,d] ----
  const unsigned short* Vz = V + hh * DH_;
  f32x4 acc[2][4];
#pragma unroll
  for (int m = 0; m < 2; ++m)
#pragma unroll
    for (int n = 0; n < 4; ++n) acc[m][n] = (f32x4){0.f, 0.f, 0.f, 0.f};

  for (int ks = 0; ks < 8; ++ks) {
    const int kb = ks * 32 + lgr * 8;
    bf16x8 bv2[4];
#pragma unroll
    for (int n = 0; n < 4; ++n) {
      const int d = n * 16 + lan;
      bf16x8 tmp;
#pragma unroll
      for (int jj = 0; jj < 8; ++jj)
        tmp[jj] = (short)Vz[(size_t)((kb + jj) * NE + nn) * 1024 + d];
      bv2[n] = tmp;
    }
    bf16x8 pa[2];
#pragma unroll
    for (int m = 0; m < 2; ++m) {
      const int r = m * 16 + lan;
      const int swz = ((r >> 2) & 3) * 16;
      pa[m] = *(const bf16x8*)&S[r * 256 + (kb ^ swz)];
    }
#pragma unroll
    for (int m = 0; m < 2; ++m)
#pragma unroll
      for (int n = 0; n < 4; ++n)
        acc[m][n] = __builtin_amdgcn_mfma_f32_16x16x32_bf16(pa[m], bv2[n], acc[m][n], 0, 0, 0);
  }
#pragma unroll
  for (int m = 0; m < 2; ++m)
#pragma unroll
    for (int n = 0; n < 4; ++n)
#pragma unroll
      for (int e = 0; e < 4; ++e) {
        const int i = i0 + m * 16 + lgr * 4 + e;
        const int d = n * 16 + lan;
        O[(size_t)(i * NE + nn) * 1024 + hh * DH_ + d] = f2bf(acc[m][n][e]);
      }
}

// ---------------------------------------------------------------------------
__global__ __launch_bounds__(256) void transpose_kernel(
    const float* __restrict__ W, unsigned short* __restrict__ WT, int Kd, int Nd)
{
  __shared__ float tile[32][33];
  const int tx = threadIdx.x & 31, ty = threadIdx.x >> 5;
  const int nIn = blockIdx.x * 32 + tx;
  const int kBase = blockIdx.y * 32;
#pragma unroll
  for (int r = 0; r < 32; r += 8)
    tile[ty + r][tx] = W[(size_t)(kBase + ty + r) * Nd + nIn];
  __syncthreads();
#pragma unroll
  for (int r = 0; r < 32; r += 8)
    WT[(size_t)(blockIdx.x * 32 + ty + r) * Kd + kBase + tx] = f2bf(tile[tx][ty + r]);
}

__global__ __launch_bounds__(256) void transpose5_kernel(
    const float* __restrict__ Wk, const float* __restrict__ Wv,
    const float* __restrict__ Wq, const float* __restrict__ Wr,
    const float* __restrict__ Wo,
    unsigned short* __restrict__ wtAll, unsigned short* __restrict__ wto)
{
  __shared__ float tile[32][33];
  const int zz = blockIdx.z;
  const float* W = (zz == 0) ? Wk : (zz == 1) ? Wv : (zz == 2) ? Wq : (zz == 3) ? Wr : Wo;
  unsigned short* WT = (zz == 4) ? wto : (wtAll + (size_t)zz * 1024 * 1024);
  const int tx = threadIdx.x & 31, ty = threadIdx.x >> 5;
  const int nIn = blockIdx.x * 32 + tx;
  const int kBase = blockIdx.y * 32;
#pragma unroll
  for (int r = 0; r < 32; r += 8)
    tile[ty + r][tx] = W[(size_t)(kBase + ty + r) * 1024 + nIn];
  __syncthreads();
#pragma unroll
  for (int r = 0; r < 32; r += 8)
    WT[(size_t)(blockIdx.x * 32 + ty + r) * 1024 + kBase + tx] = f2bf(tile[tx][ty + r]);
}

__global__ __launch_bounds__(256) void catmem_kernel(
    const float* __restrict__ mems_l, const float* __restrict__ masks,
    unsigned short* __restrict__ cat)
{
  const int idx = blockIdx.x * 256 + threadIdx.x;
  const int d = idx & 1023;
  const int r = idx >> 10;
  const int nn = r & 31, j = r >> 5;
  const float mk0 = masks[nn];
  cat[idx] = f2bf(mems_l[(size_t)(nn * M_ + j) * 1024 + d] * mk0);
}

__global__ __launch_bounds__(256) void hprep_kernel(
    const float* __restrict__ x, const float* __restrict__ ctx,
    float* __restrict__ h, unsigned short* __restrict__ catUp)
{
  const int idx = blockIdx.x * 256 + threadIdx.x;
  const float v = x[idx] + ctx[idx];
  h[idx] = v;
  catUp[idx] = f2bf(v);
}

__global__ __launch_bounds__(256) void rpos_kernel(unsigned short* __restrict__ R)
{
  const int idx = blockIdx.x * 256 + threadIdx.x;
  const int d = idx & 1023, j = idx >> 10;
  const float pos = (float)(KLEN - 1 - j);
  const int f = d & 511;
  const float inv_freq = __expf(-((float)(2 * f) * (1.f / 1024.f)) * 9.210340371976184f);
  const float ang = pos * inv_freq;
  const float v = (d < 512) ? sinf(ang) : cosf(ang);
  R[idx] = f2bf(v);
}

__global__ void ep_kernel(const float* __restrict__ masks, int* __restrict__ ep)
{
  const int nn = threadIdx.x;
  if (nn < NE) {
    int c = 0;
    for (int i = 0; i < T_; ++i) {
      c += (masks[i * NE + nn] == 0.f) ? 1 : 0;
      ep[i * NE + nn] = c;
    }
  }
}

// y = LN(a + sum_{i<NP} parts[i] + bias) * g + b
template <int NP>
__global__ __launch_bounds__(256) void ln_kernel(
    const float* __restrict__ a, const float* __restrict__ parts, size_t pstride,
    const float* __restrict__ bias,
    const float* __restrict__ g, const float* __restrict__ bb,
    float* __restrict__ outf, unsigned short* __restrict__ outbf)
{
  const int row = blockIdx.x;
  const int t = threadIdx.x, w = t >> 6, l = t & 63;
  const int c = t * 4;
  const size_t base = (size_t)row * 1024;
  f32x4 v = *(const f32x4*)&a[base + c];
#pragma unroll
  for (int i = 0; i < NP; ++i)
    v = v + *(const f32x4*)&parts[i * pstride + base + c];
  if (bias) v = v + *(const f32x4*)&bias[c];
  float s = v[0] + v[1] + v[2] + v[3];
#pragma unroll
  for (int o = 32; o; o >>= 1) s += __shfl_xor(s, o);
  __shared__ float red[8];
  if (l == 0) red[w] = s;
  __syncthreads();
  s = red[0] + red[1] + red[2] + red[3];
  const float mu = s * (1.f / 1024.f);
  f32x4 dv = v - mu;
  float s2 = dv[0]*dv[0] + dv[1]*dv[1] + dv[2]*dv[2] + dv[3]*dv[3];
#pragma unroll
  for (int o = 32; o; o >>= 1) s2 += __shfl_xor(s2, o);
  if (l == 0) red[4 + w] = s2;
  __syncthreads();
  s2 = red[4] + red[5] + red[6] + red[7];
  const float inv = rsqrtf(s2 * (1.f / 1024.f) + 1e-5f);
  f32x4 y;
#pragma unroll
  for (int q = 0; q < 4; ++q) y[q] = dv[q] * inv * g[c + q] + bb[c + q];
  *(f32x4*)&outf[base + c] = y;
  if (outbf) {
    s16x4 o4;
#pragma unroll
    for (int q = 0; q < 4; ++q) o4[q] = (short)f2bf(y[q]);
    *(s16x4*)&outbf[base + c] = o4;
  }
}

// ---------------------------------------------------------------------------
extern "C" void kernel_launch(void* const* d_in, const int* in_sizes, int n_in,
                              void* d_out, int out_size, void* d_ws, size_t ws_size,
                              hipStream_t stream)
{
  (void)in_sizes; (void)n_in; (void)out_size; (void)ws_size;
  const float* x    = (const float*)d_in[0];
  const float* ctx  = (const float*)d_in[1];
  const float* mems = (const float*)d_in[2];
  const float* masks= (const float*)d_in[3];
  const float* Wq   = (const float*)d_in[4];
  const float* Wk   = (const float*)d_in[5];
  const float* Wv   = (const float*)d_in[6];
  const float* Wr   = (const float*)d_in[7];
  const float* Wo   = (const float*)d_in[8];
  const float* W1   = (const float*)d_in[9];
  const float* b1   = (const float*)d_in[10];
  const float* W2   = (const float*)d_in[11];
  const float* b2   = (const float*)d_in[12];
  const float* ln1g = (const float*)d_in[13];
  const float* ln1b = (const float*)d_in[14];
  const float* ln2g = (const float*)d_in[15];
  const float* ln2b = (const float*)d_in[16];
  const float* rwb  = (const float*)d_in[17];
  const float* rrb  = (const float*)d_in[18];

  char* ws = (char*)d_ws;
  size_t off = 0;
  auto alloc = [&](size_t bytes) {
    char* p = ws + off;
    off += (bytes + 255) & ~(size_t)255;
    return p;
  };
  unsigned short* wtAll = (unsigned short*)alloc(4096u * 1024 * 2);  // [Wk|Wv|Wq|Wr]^T
  unsigned short* wto = (unsigned short*)alloc(1024u * 1024 * 2);
  unsigned short* wt1 = (unsigned short*)alloc(4096u * 1024 * 2);
  unsigned short* wt2 = (unsigned short*)alloc(4096u * 1024 * 2);
  unsigned short* cat = (unsigned short*)alloc((size_t)(KLEN * NE + 256) * 1024 * 2);
  unsigned short* rbf = (unsigned short*)alloc((size_t)KLEN * 1024 * 2);
  int*            epb = (int*)alloc((size_t)T_ * NE * 4);
  float*          h   = (float*)alloc((size_t)TN * 1024 * 4);
  float*          h1  = (float*)alloc((size_t)TN * 1024 * 4);
  unsigned short* qw  = (unsigned short*)alloc((size_t)TN * 1024 * 2);   // alias: h1_bf
  unsigned short* qr  = (unsigned short*)alloc((size_t)TN * 1024 * 2);
  unsigned short* kbf = (unsigned short*)alloc((size_t)KLEN * NE * 1024 * 2);
  unsigned short* vbf = (unsigned short*)alloc((size_t)KLEN * NE * 1024 * 2);
  unsigned short* ACb = (unsigned short*)alloc((size_t)NB * T_ * KLEN * 2); // alias: f1
  unsigned short* BDb = (unsigned short*)alloc((size_t)NB * T_ * KLEN * 2); // alias: part 0,1
  unsigned short* obf = (unsigned short*)alloc((size_t)TN * 1024 * 2);

  unsigned short* catUp = cat + (size_t)M_ * NE * 1024;     // h rows (4096..8191)
  unsigned short* catR  = cat + (size_t)KLEN * NE * 1024;   // R rows (8192..8447)
  unsigned short* f1 = ACb;                 // W1 out
  float* part = (float*)BDb;                // split-K partials (2x TN*1024 f32)
  unsigned short* h1bf = qw;                // qw dead after attn

  rpos_kernel<<<KLEN * 1024 / 256, 256, 0, stream>>>(catR);
  ep_kernel<<<1, 64, 0, stream>>>(masks, epb);
  hprep_kernel<<<TN * 1024 / 256, 256, 0, stream>>>(x, ctx, h, catUp);

  for (int l = 0; l < L_; ++l) {
    const size_t wOff = (size_t)l * 1024 * 1024;
    const size_t wOffBig = (size_t)l * 1024 * 4096;
    transpose5_kernel<<<dim3(32, 32, 5), 256, 0, stream>>>(
        Wk + wOff, Wv + wOff, Wq + wOff, Wr + wOff, Wo + wOff, wtAll, wto);
    transpose_kernel<<<dim3(128, 32), 256, 0, stream>>>(W1 + wOffBig, wt1, 1024, 4096);
    transpose_kernel<<<dim3(32, 128), 256, 0, stream>>>(W2 + wOffBig, wt2, 4096, 1024);
    catmem_kernel<<<M_ * NE * 1024 / 256, 256, 0, stream>>>(
        mems + (size_t)l * NE * M_ * 1024, masks, cat);

    // fused k|v|q|r projection (1296 blocks, 128^2 tiles, 2-phase)
    gemm_proj<<<1296, 256, 0, stream>>>(cat, wtAll, kbf, vbf, qw, qr, rbf, rwb, rrb);

    // fully fused attention (scores + rel_shift + masked softmax + PV)
    attn_kernel<<<NB, 256, 0, stream>>>(qw, qr, kbf, rbf, epb, vbf, obf);

    // output projection, split-K=2 -> f32 partials; reduce fused into LN1
    gemm_bt<0><<<dim3(8, 32, 2), 256, 0, stream>>>(obf, 1024, 0, 512,
                                                   wto, 1024, 0, 512,
                                                   part, 1024, TN * 1024, nullptr, 8, 2);
    ln_kernel<2><<<TN, 256, 0, stream>>>(h, part, (size_t)TN * 1024, nullptr,
                                         ln1g + l * 1024, ln1b + l * 1024, h1, h1bf);

    // FFN
    gemm_bt<2><<<dim3(32, 32, 1), 256, 0, stream>>>(h1bf, 1024, 0, 0, wt1, 1024, 0, 0,
                                                    f1, 4096, 0, b1 + l * 4096, 16, 1);
    gemm_bt<0><<<dim3(8, 32, 2), 256, 0, stream>>>(f1, 4096, 0, 2048,
                                                   wt2, 4096, 0, 2048,
                                                   part, 1024, TN * 1024, nullptr, 32, 2);
    ln_kernel<2><<<TN, 256, 0, stream>>>(h1, part, (size_t)TN * 1024, b2 + l * 1024,
                                         ln2g + l * 1024, ln2b + l * 1024,
                                         (l == L_ - 1) ? (float*)d_out : h, catUp);
  }
}